// Round 10
// baseline (1864.501 us; speedup 1.0000x reference)
//
#include <hip/hip_runtime.h>
#include <hip/hip_cooperative_groups.h>

namespace cg = cooperative_groups;

// GNN_2911987826770: 6x GraphConv(add)+BN(train)+ReLU, mean-pool, linear.
// R10: whole layer loop + pool + classifier fused into ONE persistent
//      cooperative kernel (grid.sync between phases) — kills ~19 dispatch
//      boundaries. Fast thread-serial scan (also writes cursor). Fallback to
//      the proven R9 multi-dispatch path if cooperative launch fails.

typedef unsigned short u16;
typedef unsigned int u32;
typedef __attribute__((ext_vector_type(8))) short bf16x8;    // 8 bf16 = 4 VGPRs
typedef __attribute__((ext_vector_type(16))) float f32x16;   // 32x32 acc

#define DFEAT 512
#define KDIM 1024
#define NLAYER 6
#define NGRAPH 64
#define NCLS 10
#define BN_EPS 1e-5f
#define GCAP 1536
#define BM 128
#define BN 128
#define BK 64
#define CSTR 132
#define SHBYTES (BM * CSTR * 2 + 2 * BN * 4)   // 33792 + 1024 = 34816

__device__ __forceinline__ float bf_lo(u32 u) { union { u32 i; float f; } v; v.i = u << 16; return v.f; }
__device__ __forceinline__ float bf_hi(u32 u) { union { u32 i; float f; } v; v.i = u & 0xFFFF0000u; return v.f; }
__device__ __forceinline__ u16 f2bf(float f) {           // round-to-nearest-even
  union { float f; u32 i; } v; v.f = f;
  u32 r = v.i + 0x7FFFu + ((v.i >> 16) & 1u);
  return (u16)(r >> 16);
}
__device__ __forceinline__ u32 pack2(float lo, float hi) {
  return (u32)f2bf(lo) | ((u32)f2bf(hi) << 16);
}

__device__ __forceinline__ void gload_lds16(const u16* g, u16* lds_base) {
  __builtin_amdgcn_global_load_lds(
      (const __attribute__((address_space(1))) u32*)g,
      (__attribute__((address_space(3))) u32*)lds_base, 16, 0, 0);
}

// ---------------- CSR build ----------------
__global__ void hist_kernel(const int* __restrict__ ei, int* __restrict__ counts, int E) {
  int e = blockIdx.x * 256 + threadIdx.x;
  if (e < E) atomicAdd(&counts[ei[E + e]], 1);   // row 1 of edge_index = dst
}

// thread-serial scan: 20 elems/thread + one 1024-wide block scan. Writes
// row_ptr AND cursor (scatter's starting offsets) — one dispatch, no memcpy.
#define SCHUNK 20
__global__ __launch_bounds__(1024) void scan_kernel(const int* __restrict__ counts,
                                                    int* __restrict__ row_ptr,
                                                    int* __restrict__ cursor, int n) {
  __shared__ int part[1024];
  int tid = threadIdx.x;
  int base = tid * SCHUNK;
  int loc[SCHUNK];
  int s = 0;
#pragma unroll
  for (int i = 0; i < SCHUNK; i++) {
    int idx = base + i;
    int v = (idx < n) ? counts[idx] : 0;
    loc[i] = s; s += v;
  }
  part[tid] = s;
  __syncthreads();
  int x = s;
  for (int off = 1; off < 1024; off <<= 1) {
    int t = (tid >= off) ? part[tid - off] : 0;
    __syncthreads();
    x += t;
    part[tid] = x;
    __syncthreads();
  }
  int offset = x - s;                           // exclusive prefix of this chunk
#pragma unroll
  for (int i = 0; i < SCHUNK; i++) {
    int idx = base + i;
    if (idx < n) { int v = offset + loc[i]; row_ptr[idx] = v; cursor[idx] = v; }
  }
  if (tid == 1023) row_ptr[n] = offset + s;
}

__global__ void scatter_kernel(const int* __restrict__ ei, int* __restrict__ cursor,
                               int* __restrict__ csr_src, int E) {
  int e = blockIdx.x * 256 + threadIdx.x;
  if (e < E) {
    int d = ei[E + e];
    int pos = atomicAdd(&cursor[d], 1);
    csr_src[pos] = ei[e];                        // row 0 = src
  }
}

// ---------------- weight / input conversion ----------------
__global__ void wconv_kernel(const float* __restrict__ Wrel, const float* __restrict__ Wroot,
                             u16* __restrict__ Wt) {
  int idx = blockIdx.x * 256 + threadIdx.x;      // 6*512*1024 total, k fastest
  int k = idx & 1023;
  int n = (idx >> 10) & 511;
  int l = idx >> 19;
  float v = (k < DFEAT) ? Wrel[((size_t)l * DFEAT + k) * DFEAT + n]
                        : Wroot[((size_t)l * DFEAT + (k - DFEAT)) * DFEAT + n];
  Wt[idx] = f2bf(v);
}

__global__ void xconv_kernel(const float* __restrict__ x, u16* __restrict__ A, int M) {
  int idx = blockIdx.x * 256 + threadIdx.x;      // each thread: 4 cols
  int row = idx >> 7;
  int c4 = (idx & 127) * 4;
  if (row >= M) return;
  float4 v = *(const float4*)&x[(size_t)row * DFEAT + c4];
  uint2 o; o.x = pack2(v.x, v.y); o.y = pack2(v.z, v.w);
  *(uint2*)&A[(size_t)row * KDIM + DFEAT + c4] = o;
}

// ---------------- phase bodies (shared by mega kernel and fallback) ----------------
__device__ __forceinline__ void add8(uint4 v, float* a) {
  a[0] += bf_lo(v.x); a[1] += bf_hi(v.x);
  a[2] += bf_lo(v.y); a[3] += bf_hi(v.y);
  a[4] += bf_lo(v.z); a[5] += bf_hi(v.z);
  a[6] += bf_lo(v.w); a[7] += bf_hi(v.w);
}

// vb: slice = vb&7 (XCD), rows [(vb>>3)*32, +32). NO early returns past syncs.
__device__ __forceinline__ void gather_body(int vb, u16* __restrict__ A,
                                            const int* __restrict__ row_ptr,
                                            const int* __restrict__ csr_src, int n,
                                            int* sidx) {
  int slice = vb & 7;
  int grp = vb >> 3;
  int tid = threadIdx.x;
  int r0 = grp * 32;
  int rend = (r0 + 32 < n) ? (r0 + 32) : n;
  int wbeg = row_ptr[r0], wend = row_ptr[rend];
  int cnt = wend - wbeg;
  bool lds_ok = (cnt <= GCAP);
  __syncthreads();                              // protect sidx from prior readers
  if (lds_ok)
    for (int t = tid; t < cnt; t += 256) sidx[t] = csr_src[wbeg + t];
  __syncthreads();

  int wid = tid >> 6, lane = tid & 63;
  int dsub = lane >> 3, fl = lane & 7;
  int dst = r0 + wid * 8 + dsub;
  if (dst < n) {
    int cc = slice * 64 + fl * 8;
    const u16* Sx = A + DFEAT + cc;             // x-part base (+col), stride KDIM
    int db = row_ptr[dst], de = row_ptr[dst + 1];
    float a[8] = {};
    if (lds_ok) {
      int e = db - wbeg, ee = de - wbeg;
      for (; e + 7 < ee; e += 8) {              // 8 loads in flight
        int s0 = sidx[e + 0], s1 = sidx[e + 1], s2 = sidx[e + 2], s3 = sidx[e + 3];
        int s4 = sidx[e + 4], s5 = sidx[e + 5], s6 = sidx[e + 6], s7 = sidx[e + 7];
        uint4 v0 = *(const uint4*)&Sx[(size_t)s0 * KDIM];
        uint4 v1 = *(const uint4*)&Sx[(size_t)s1 * KDIM];
        uint4 v2 = *(const uint4*)&Sx[(size_t)s2 * KDIM];
        uint4 v3 = *(const uint4*)&Sx[(size_t)s3 * KDIM];
        uint4 v4 = *(const uint4*)&Sx[(size_t)s4 * KDIM];
        uint4 v5 = *(const uint4*)&Sx[(size_t)s5 * KDIM];
        uint4 v6 = *(const uint4*)&Sx[(size_t)s6 * KDIM];
        uint4 v7 = *(const uint4*)&Sx[(size_t)s7 * KDIM];
        add8(v0, a); add8(v1, a); add8(v2, a); add8(v3, a);
        add8(v4, a); add8(v5, a); add8(v6, a); add8(v7, a);
      }
      for (; e < ee; ++e) {
        uint4 v = *(const uint4*)&Sx[(size_t)sidx[e] * KDIM];
        add8(v, a);
      }
    } else {
      for (int e = db; e < de; ++e) {
        uint4 v = *(const uint4*)&Sx[(size_t)csr_src[e] * KDIM];
        add8(v, a);
      }
    }
    uint4 o;
    o.x = pack2(a[0], a[1]); o.y = pack2(a[2], a[3]);
    o.z = pack2(a[4], a[5]); o.w = pack2(a[6], a[7]);
    *(uint4*)&A[(size_t)dst * KDIM + cc] = o;
  }
}

// 128x128 tile, BK=64, XOR-swizzled staging, 2x2 mfma_32x32x16 per wave,
// LDS-staged coalesced bf16 epilogue + BN partial stats. Block-uniform guard.
__device__ void gemm_body(int lin, const u16* __restrict__ A, const u16* __restrict__ Bt,
                          const float* __restrict__ bias, u16* __restrict__ Hb,
                          float* __restrict__ sums, int M, u16* smem, float* sred) {
  const int bx = ((lin >> 5) << 3) + (lin & 7);
  const int by = (lin >> 3) & 3;
  const int m0 = bx * BM;
  if (m0 >= M) return;                          // block-uniform; fn-return only
  const int n0 = by * BN;

  u16* As = smem;
  u16* Bs = smem + BM * BK;
  const int tid = threadIdx.x;
  const int wid = tid >> 6, lane = tid & 63;
  const int wm = wid >> 1, wn = wid & 1;
  const int l31 = lane & 31, half = lane >> 5;

  if (tid < 2 * BN) sred[tid] = 0.f;

  const int dr = lane >> 3;
  const int gcol = ((lane & 7) ^ dr) * 8;
  int arow[4], brow[4];
#pragma unroll
  for (int t = 0; t < 4; t++) {
    int r = wid * 32 + t * 8 + dr;
    int ar = m0 + r; if (ar >= M) ar = M - 1;
    arow[t] = ar;
    brow[t] = n0 + r;
  }

  f32x16 acc[2][2] = {};

  for (int k0 = 0; k0 < KDIM; k0 += BK) {
    __syncthreads();
#pragma unroll
    for (int t = 0; t < 4; t++)
      gload_lds16(&A[(size_t)arow[t] * KDIM + k0 + gcol], &As[(wid * 32 + t * 8) * BK]);
#pragma unroll
    for (int t = 0; t < 4; t++)
      gload_lds16(&Bt[(size_t)brow[t] * KDIM + k0 + gcol], &Bs[(wid * 32 + t * 8) * BK]);
    __syncthreads();
#pragma unroll
    for (int ks = 0; ks < 4; ks++) {
      int slot = ((ks * 2 + half) ^ (l31 & 7)) * 8;
      bf16x8 a0 = *(const bf16x8*)&As[(wm * 64 + l31) * BK + slot];
      bf16x8 a1 = *(const bf16x8*)&As[(wm * 64 + 32 + l31) * BK + slot];
      bf16x8 b0 = *(const bf16x8*)&Bs[(wn * 64 + l31) * BK + slot];
      bf16x8 b1 = *(const bf16x8*)&Bs[(wn * 64 + 32 + l31) * BK + slot];
      acc[0][0] = __builtin_amdgcn_mfma_f32_32x32x16_bf16(a0, b0, acc[0][0], 0, 0, 0);
      acc[0][1] = __builtin_amdgcn_mfma_f32_32x32x16_bf16(a0, b1, acc[0][1], 0, 0, 0);
      acc[1][0] = __builtin_amdgcn_mfma_f32_32x32x16_bf16(a1, b0, acc[1][0], 0, 0, 0);
      acc[1][1] = __builtin_amdgcn_mfma_f32_32x32x16_bf16(a1, b1, acc[1][1], 0, 0, 0);
    }
  }

  __syncthreads();

#pragma unroll
  for (int nt = 0; nt < 2; nt++) {
    int colt = wn * 64 + nt * 32 + l31;
    float bv = bias[n0 + colt];
    float s = 0.f, s2 = 0.f;
#pragma unroll
    for (int mt = 0; mt < 2; mt++) {
      int rbase = wm * 64 + mt * 32 + half * 4;
#pragma unroll
      for (int reg = 0; reg < 16; reg++) {
        int rowt = rbase + (reg & 3) + 8 * (reg >> 2);
        float v = acc[mt][nt][reg] + bv;
        smem[rowt * CSTR + colt] = f2bf(v);
        if (m0 + rowt < M) { s += v; s2 += v * v; }
      }
    }
    s  += __shfl_xor(s, 32);
    s2 += __shfl_xor(s2, 32);
    if (half == 0) {
      atomicAdd(&sred[colt], s);
      atomicAdd(&sred[BN + colt], s2);
    }
  }
  __syncthreads();

  const int rsub = tid >> 4;
  const int c8 = (tid & 15) * 8;
#pragma unroll
  for (int it = 0; it < 8; it++) {
    int rowt = it * 16 + rsub;
    int grow = m0 + rowt;
    if (grow < M) {
      uint4 v = *(const uint4*)&smem[rowt * CSTR + c8];
      *(uint4*)&Hb[(size_t)grow * DFEAT + n0 + c8] = v;
    }
  }
  if (tid < BN) {
    atomicAdd(&sums[n0 + tid], sred[tid]);
    atomicAdd(&sums[DFEAT + n0 + tid], sred[BN + tid]);
  }
}

__device__ __forceinline__ void norm_body(int idx, const u16* __restrict__ Hb,
                                          const float* __restrict__ sums,
                                          const float* __restrict__ gamma,
                                          const float* __restrict__ beta,
                                          u16* __restrict__ A, int M, float invN) {
  int row = idx >> 6;
  int c8 = (idx & 63) * 8;
  if (row >= M) return;
  float sc[8], sh[8];
#pragma unroll
  for (int j = 0; j < 8; j++) {
    int c = c8 + j;
    float mu = sums[c] * invN;
    float var = sums[DFEAT + c] * invN - mu * mu;
    float s = gamma[c] * rsqrtf(var + BN_EPS);
    sc[j] = s;
    sh[j] = beta[c] - mu * s;
  }
  uint4 h = *(const uint4*)&Hb[(size_t)row * DFEAT + c8];
  float x0 = fmaxf(bf_lo(h.x) * sc[0] + sh[0], 0.f);
  float x1 = fmaxf(bf_hi(h.x) * sc[1] + sh[1], 0.f);
  float x2 = fmaxf(bf_lo(h.y) * sc[2] + sh[2], 0.f);
  float x3 = fmaxf(bf_hi(h.y) * sc[3] + sh[3], 0.f);
  float x4 = fmaxf(bf_lo(h.z) * sc[4] + sh[4], 0.f);
  float x5 = fmaxf(bf_hi(h.z) * sc[5] + sh[5], 0.f);
  float x6 = fmaxf(bf_lo(h.w) * sc[6] + sh[6], 0.f);
  float x7 = fmaxf(bf_hi(h.w) * sc[7] + sh[7], 0.f);
  uint4 o; o.x = pack2(x0, x1); o.y = pack2(x2, x3);
  o.z = pack2(x4, x5); o.w = pack2(x6, x7);
  *(uint4*)&A[(size_t)row * KDIM + DFEAT + c8] = o;
}

__device__ __forceinline__ int lower_bound_dev(const int* a, int n, int v) {
  int lo = 0, hi = n;
  while (lo < hi) { int mid = (lo + hi) >> 1; if (a[mid] < v) lo = mid + 1; else hi = mid; }
  return lo;
}

// 256-thread pool: 4 row-streams x 64 lanes (8 cols each); fused finalize+affine+ReLU.
__device__ void pool_body(int g, const u16* __restrict__ Hb, const float* __restrict__ sums,
                          const float* __restrict__ gamma, const float* __restrict__ beta,
                          const int* __restrict__ batch, float* __restrict__ pooled,
                          int n, float invN, float* red) {
  int tid = threadIdx.x;
  red[tid] = 0.f; red[tid + 256] = 0.f;
  int lo = lower_bound_dev(batch, n, g);
  int hi = lower_bound_dev(batch, n, g + 1);
  int rowOff = tid >> 6, lane = tid & 63;
  int c0 = lane * 8;
  float sc[8], sh[8];
#pragma unroll
  for (int j = 0; j < 8; j++) {
    int c = c0 + j;
    float mu = sums[c] * invN;
    float var = sums[DFEAT + c] * invN - mu * mu;
    float s = gamma[c] * rsqrtf(var + BN_EPS);
    sc[j] = s;
    sh[j] = beta[c] - mu * s;
  }
  float a[8] = {};
  for (int r = lo + rowOff; r < hi; r += 4) {
    uint4 v = *(const uint4*)&Hb[(size_t)r * DFEAT + c0];
    float e0 = bf_lo(v.x), e1 = bf_hi(v.x), e2 = bf_lo(v.y), e3 = bf_hi(v.y);
    float e4 = bf_lo(v.z), e5 = bf_hi(v.z), e6 = bf_lo(v.w), e7 = bf_hi(v.w);
    a[0] += fmaxf(e0 * sc[0] + sh[0], 0.f); a[1] += fmaxf(e1 * sc[1] + sh[1], 0.f);
    a[2] += fmaxf(e2 * sc[2] + sh[2], 0.f); a[3] += fmaxf(e3 * sc[3] + sh[3], 0.f);
    a[4] += fmaxf(e4 * sc[4] + sh[4], 0.f); a[5] += fmaxf(e5 * sc[5] + sh[5], 0.f);
    a[6] += fmaxf(e6 * sc[6] + sh[6], 0.f); a[7] += fmaxf(e7 * sc[7] + sh[7], 0.f);
  }
  __syncthreads();
#pragma unroll
  for (int j = 0; j < 8; j++) atomicAdd(&red[c0 + j], a[j]);
  __syncthreads();
  float cnt = fmaxf((float)(hi - lo), 1.0f);
  pooled[g * DFEAT + tid] = red[tid] / cnt;
  pooled[g * DFEAT + tid + 256] = red[tid + 256] / cnt;
  __syncthreads();
}

__device__ void final_body(const float* __restrict__ pooled, const float* __restrict__ lin_w,
                           const float* __restrict__ lin_b, float* __restrict__ out) {
  int tid = threadIdx.x;
  if (tid >= 64) return;
  for (int g = 0; g < NGRAPH; ++g) {
    float acc[NCLS] = {};
    float4 p0 = *(const float4*)&pooled[g * DFEAT + tid * 8];
    float4 p1 = *(const float4*)&pooled[g * DFEAT + tid * 8 + 4];
    float pv[8] = {p0.x, p0.y, p0.z, p0.w, p1.x, p1.y, p1.z, p1.w};
#pragma unroll
    for (int j = 0; j < 8; j++) {
      int k = tid * 8 + j;
#pragma unroll
      for (int c = 0; c < NCLS; c++) acc[c] += pv[j] * lin_w[k * NCLS + c];
    }
#pragma unroll
    for (int off = 32; off > 0; off >>= 1)
#pragma unroll
      for (int c = 0; c < NCLS; c++) acc[c] += __shfl_down(acc[c], off);
    if (tid == 0)
#pragma unroll
      for (int c = 0; c < NCLS; c++) out[g * NCLS + c] = acc[c] + lin_b[c];
  }
}

// ---------------- persistent cooperative mega-kernel ----------------
__global__ __launch_bounds__(256, 3) void fused_layers(
    u16* A, u16* Hb, const u16* Wt, const float* b_rel,
    const float* gamma, const float* beta,
    const int* row_ptr, const int* csr_src, float* sums,
    const int* batch, float* pooled, const float* lin_w, const float* lin_b,
    float* out, int N, float invN) {
  __shared__ __align__(16) char shbuf[SHBYTES];   // phase-aliased: sidx/As+Bs+C/red
  cg::grid_group grid = cg::this_grid();
  const int nb = gridDim.x;                       // multiple of 8 (host guarantees)
  const int ngrp8 = ((N + 31) / 32) * 8;
  const int gtiles = (((N + BM - 1) / BM + 7) / 8) * 8 * 4;
  const int nvb = (N * 64 + 255) / 256;
  int* sidx = (int*)shbuf;
  u16* smem = (u16*)shbuf;
  float* sred = (float*)(shbuf + BM * CSTR * 2);
  float* red = (float*)shbuf;

  for (int l = 0; l < NLAYER; ++l) {
    for (int vb = blockIdx.x; vb < ngrp8; vb += nb)
      gather_body(vb, A, row_ptr, csr_src, N, sidx);
    grid.sync();

    const u16* Bt = Wt + (size_t)l * DFEAT * KDIM;
    const float* bias = b_rel + (size_t)l * DFEAT;
    float* sums_l = sums + (size_t)l * 2 * DFEAT;
    for (int vb = blockIdx.x; vb < gtiles; vb += nb) {
      gemm_body(vb, A, Bt, bias, Hb, sums_l, N, smem, sred);
      __syncthreads();
    }
    grid.sync();

    if (l < NLAYER - 1) {
      const float* g_l = gamma + (size_t)l * DFEAT;
      const float* be_l = beta + (size_t)l * DFEAT;
      for (int vb = blockIdx.x; vb < nvb; vb += nb)
        norm_body(vb * 256 + (int)threadIdx.x, Hb, sums_l, g_l, be_l, A, N, invN);
      grid.sync();
    }
  }

  const float* sums_last = sums + (size_t)(NLAYER - 1) * 2 * DFEAT;
  for (int g = blockIdx.x; g < NGRAPH; g += nb)
    pool_body(g, Hb, sums_last, gamma + (size_t)(NLAYER - 1) * DFEAT,
              beta + (size_t)(NLAYER - 1) * DFEAT, batch, pooled, N, invN, red);
  grid.sync();
  if (blockIdx.x == 0) final_body(pooled, lin_w, lin_b, out);
}

// ---------------- fallback standalone kernels (R9 path) ----------------
__global__ __launch_bounds__(256) void gather_kernel(u16* A, const int* row_ptr,
                                                     const int* csr_src, int n) {
  __shared__ int sidx[GCAP];
  gather_body(blockIdx.x, A, row_ptr, csr_src, n, sidx);
}

__global__ __launch_bounds__(256, 4) void gemm_kernel(const u16* A, const u16* Bt,
                                                      const float* bias, u16* Hb,
                                                      float* sums, int M) {
  __shared__ __align__(16) char shb[SHBYTES];
  gemm_body(blockIdx.x, A, Bt, bias, Hb, sums, M, (u16*)shb, (float*)(shb + BM * CSTR * 2));
}

__global__ void norm_kernel(const u16* Hb, const float* sums, const float* gamma,
                            const float* beta, u16* A, int M, float invN) {
  norm_body(blockIdx.x * 256 + (int)threadIdx.x, Hb, sums, gamma, beta, A, M, invN);
}

__global__ __launch_bounds__(256) void pool_kernel(const u16* Hb, const float* sums,
                                                   const float* gamma, const float* beta,
                                                   const int* batch, float* pooled,
                                                   int n, float invN) {
  __shared__ float red[DFEAT];
  pool_body(blockIdx.x, Hb, sums, gamma, beta, batch, pooled, n, invN, red);
}

__global__ __launch_bounds__(64) void final_kernel(const float* pooled, const float* lin_w,
                                                   const float* lin_b, float* out) {
  final_body(pooled, lin_w, lin_b, out);
}

// ---------------- orchestration ----------------
extern "C" void kernel_launch(void* const* d_in, const int* in_sizes, int n_in,
                              void* d_out, int out_size, void* d_ws, size_t ws_size,
                              hipStream_t stream) {
  const float* x      = (const float*)d_in[0];
  const int*   ei     = (const int*)d_in[1];
  const int*   batch  = (const int*)d_in[2];
  const float* W_rel  = (const float*)d_in[3];
  const float* b_rel  = (const float*)d_in[4];
  const float* W_root = (const float*)d_in[5];
  const float* gamma  = (const float*)d_in[6];
  const float* beta   = (const float*)d_in[7];
  const float* lin_w  = (const float*)d_in[8];
  const float* lin_b  = (const float*)d_in[9];
  float* out = (float*)d_out;

  const int N = in_sizes[0] / DFEAT;    // 20000
  const int E = in_sizes[1] / 2;        // 320000

  char* p = (char*)d_ws;
  u16*   A       = (u16*)p;    p += (size_t)N * KDIM * 2;
  u16*   Hb      = (u16*)p;    p += (size_t)N * DFEAT * 2;
  u16*   Wt      = (u16*)p;    p += (size_t)NLAYER * DFEAT * KDIM * 2;
  int*   row_ptr = (int*)p;    p += ((size_t)(N + 1) * 4 + 15) / 16 * 16;
  int*   cursor  = (int*)p;    p += (size_t)N * 4;   // doubles as counts
  int*   csr_src = (int*)p;    p += (size_t)E * 4;
  float* sums    = (float*)p;  p += (size_t)NLAYER * 2 * DFEAT * 4;
  float* pooled  = (float*)p;  p += (size_t)NGRAPH * DFEAT * 4;

  const float invN = 1.0f / (float)N;

  hipMemsetAsync(cursor, 0, (size_t)N * 4, stream);
  hipMemsetAsync(sums, 0, (size_t)NLAYER * 2 * DFEAT * 4, stream);

  // ---- CSR build (scan also writes cursor = scatter offsets) ----
  hist_kernel<<<(E + 255) / 256, 256, 0, stream>>>(ei, cursor, E);
  scan_kernel<<<1, 1024, 0, stream>>>(cursor, row_ptr, cursor, N);
  scatter_kernel<<<(E + 255) / 256, 256, 0, stream>>>(ei, cursor, csr_src, E);

  // ---- weight + input conversion ----
  wconv_kernel<<<(NLAYER * DFEAT * KDIM) / 256, 256, 0, stream>>>(W_rel, W_root, Wt);
  xconv_kernel<<<(N * 128 + 255) / 256, 256, 0, stream>>>(x, A, N);

  // ---- cooperative mega-kernel for the layer loop + pool + classifier ----
  int maxB = 0;
  hipError_t occErr = hipOccupancyMaxActiveBlocksPerMultiprocessor(&maxB, fused_layers, 256, 0);
  int grid = 0;
  if (occErr == hipSuccess && maxB > 0) {
    grid = maxB * 256;                 // 256 CUs
    if (grid > 1024) grid = 1024;
    grid &= ~7;                        // multiple of 8: slice = blockIdx&7 stays fixed
  }
  bool coop_done = false;
  if (grid >= 256) {
    u16* A_ = A; u16* Hb_ = Hb; const u16* Wt_ = Wt;
    const float* br_ = b_rel; const float* g_ = gamma; const float* be_ = beta;
    const int* rp_ = row_ptr; const int* cs_ = csr_src; float* su_ = sums;
    const int* ba_ = batch; float* po_ = pooled;
    const float* lw_ = lin_w; const float* lb_ = lin_b; float* out_ = out;
    int N_ = N; float invN_ = invN;
    void* args[] = {&A_, &Hb_, &Wt_, &br_, &g_, &be_, &rp_, &cs_, &su_,
                    &ba_, &po_, &lw_, &lb_, &out_, &N_, &invN_};
    hipError_t e = hipLaunchCooperativeKernel((const void*)fused_layers,
                                              dim3(grid), dim3(256), args, 0, stream);
    coop_done = (e == hipSuccess);
  }

  if (!coop_done) {                    // proven R9 multi-dispatch path
    const int ngrp8 = ((N + 31) / 32) * 8;
    const int gtiles = (((N + BM - 1) / BM + 7) / 8) * 8 * 4;
    for (int l = 0; l < NLAYER; ++l) {
      float* sums_l = sums + (size_t)l * 2 * DFEAT;
      gather_kernel<<<ngrp8, 256, 0, stream>>>(A, row_ptr, csr_src, N);
      gemm_kernel<<<gtiles, 256, 0, stream>>>(A, Wt + (size_t)l * DFEAT * KDIM,
                                              b_rel + (size_t)l * DFEAT, Hb, sums_l, N);
      if (l < NLAYER - 1)
        norm_kernel<<<(N * 64 + 255) / 256, 256, 0, stream>>>(
            Hb, sums_l, gamma + (size_t)l * DFEAT, beta + (size_t)l * DFEAT, A, N, invN);
    }
    pool_kernel<<<NGRAPH, 256, 0, stream>>>(Hb, sums + (size_t)(NLAYER - 1) * 2 * DFEAT,
                                            gamma + (size_t)(NLAYER - 1) * DFEAT,
                                            beta + (size_t)(NLAYER - 1) * DFEAT,
                                            batch, pooled, N, invN);
    final_kernel<<<1, 64, 0, stream>>>(pooled, lin_w, lin_b, out);
  }
}

// Round 11
// 601.737 us; speedup vs baseline: 3.0985x; 3.0985x over previous
//
#include <hip/hip_runtime.h>

// GNN_2911987826770: 6x GraphConv(add)+BN(train)+ReLU, mean-pool, linear.
// R11: cooperative fusion reverted (grid.sync ~100us each on 8-XCD MI355X —
//      dispatch boundaries are 20x cheaper). R9 structure + merged prologue
//      (hist|wconv|xconv in one block-partitioned kernel, scan writes cursor)
//      + float2 (pk_add) accumulation in gather.

typedef unsigned short u16;
typedef unsigned int u32;
typedef __attribute__((ext_vector_type(8))) short bf16x8;    // 8 bf16 = 4 VGPRs
typedef __attribute__((ext_vector_type(16))) float f32x16;   // 32x32 acc

#define DFEAT 512
#define KDIM 1024
#define NLAYER 6
#define NGRAPH 64
#define NCLS 10
#define BN_EPS 1e-5f

__device__ __forceinline__ float bf_lo(u32 u) { union { u32 i; float f; } v; v.i = u << 16; return v.f; }
__device__ __forceinline__ float bf_hi(u32 u) { union { u32 i; float f; } v; v.i = u & 0xFFFF0000u; return v.f; }
__device__ __forceinline__ u16 f2bf(float f) {           // round-to-nearest-even
  union { float f; u32 i; } v; v.f = f;
  u32 r = v.i + 0x7FFFu + ((v.i >> 16) & 1u);
  return (u16)(r >> 16);
}
__device__ __forceinline__ u32 pack2(float lo, float hi) {
  return (u32)f2bf(lo) | ((u32)f2bf(hi) << 16);
}

// async global->LDS, 16B per lane. LDS dest is wave-uniform base + lane*16.
__device__ __forceinline__ void gload_lds16(const u16* g, u16* lds_base) {
  __builtin_amdgcn_global_load_lds(
      (const __attribute__((address_space(1))) u32*)g,
      (__attribute__((address_space(3))) u32*)lds_base, 16, 0, 0);
}

// ---------------- merged prologue: hist | wconv | xconv ----------------
__global__ void prep_kernel(const int* __restrict__ ei, int* __restrict__ counts, int E,
                            const float* __restrict__ Wrel, const float* __restrict__ Wroot,
                            u16* __restrict__ Wt,
                            const float* __restrict__ x, u16* __restrict__ A, int M,
                            int histB, int wB) {
  int b = blockIdx.x;
  if (b < histB) {                               // edge histogram (dst counts)
    int e = b * 256 + threadIdx.x;
    if (e < E) atomicAdd(&counts[ei[E + e]], 1);
  } else if (b < histB + wB) {                   // Wt[l][n][k] = bf16(W[l][k][n])
    int idx = (b - histB) * 256 + threadIdx.x;
    int k = idx & 1023;
    int n = (idx >> 10) & 511;
    int l = idx >> 19;
    float v = (k < DFEAT) ? Wrel[((size_t)l * DFEAT + k) * DFEAT + n]
                          : Wroot[((size_t)l * DFEAT + (k - DFEAT)) * DFEAT + n];
    Wt[idx] = f2bf(v);
  } else {                                       // x f32 -> bf16 into A[:,512:1024]
    int idx = (b - histB - wB) * 256 + threadIdx.x;
    int row = idx >> 7;
    int c4 = (idx & 127) * 4;
    if (row < M) {
      float4 v = *(const float4*)&x[(size_t)row * DFEAT + c4];
      uint2 o; o.x = pack2(v.x, v.y); o.y = pack2(v.z, v.w);
      *(uint2*)&A[(size_t)row * KDIM + DFEAT + c4] = o;
    }
  }
}

// thread-serial scan: 20 elems/thread + one 1024-wide block scan. Writes
// row_ptr AND cursor (scatter's starting offsets) — one dispatch, no memcpy.
#define SCHUNK 20
__global__ __launch_bounds__(1024) void scan_kernel(const int* __restrict__ counts,
                                                    int* __restrict__ row_ptr,
                                                    int* __restrict__ cursor, int n) {
  __shared__ int part[1024];
  int tid = threadIdx.x;
  int base = tid * SCHUNK;
  int loc[SCHUNK];
  int s = 0;
#pragma unroll
  for (int i = 0; i < SCHUNK; i++) {
    int idx = base + i;
    int v = (idx < n) ? counts[idx] : 0;
    loc[i] = s; s += v;
  }
  part[tid] = s;
  __syncthreads();
  int x = s;
  for (int off = 1; off < 1024; off <<= 1) {
    int t = (tid >= off) ? part[tid - off] : 0;
    __syncthreads();
    x += t;
    part[tid] = x;
    __syncthreads();
  }
  int offset = x - s;                           // exclusive prefix of this chunk
#pragma unroll
  for (int i = 0; i < SCHUNK; i++) {
    int idx = base + i;
    if (idx < n) { int v = offset + loc[i]; row_ptr[idx] = v; cursor[idx] = v; }
  }
  if (tid == 1023) row_ptr[n] = offset + s;
}

__global__ void scatter_kernel(const int* __restrict__ ei, int* __restrict__ cursor,
                               int* __restrict__ csr_src, int E) {
  int e = blockIdx.x * 256 + threadIdx.x;
  if (e < E) {
    int d = ei[E + e];
    int pos = atomicAdd(&cursor[d], 1);
    csr_src[pos] = ei[e];                        // row 0 = src
  }
}

// ---------------- feature-sliced gather (segment_sum by dst) ----------------
// float2 accumulators: adjacent-pair adds can fuse into v_pk_add_f32.
__device__ __forceinline__ void add8(uint4 v, float2* a) {
  a[0] += make_float2(bf_lo(v.x), bf_hi(v.x));
  a[1] += make_float2(bf_lo(v.y), bf_hi(v.y));
  a[2] += make_float2(bf_lo(v.z), bf_hi(v.z));
  a[3] += make_float2(bf_lo(v.w), bf_hi(v.w));
}

// block b: slice = b&7 (-> XCD round-robin), rows [(b>>3)*32, +32).
// 4 waves/block; wave = 8 dst rows x 8 lanes (8 cols, 16B loads).
// Per-XCD read footprint = 20000 x 128B = 2.5MB -> L2-resident.
// 6KB LDS index window; NO min-wave launch_bounds (R8: a 32-VGPR cap
// spills the 8-deep load pipe — ILP beats occupancy here).
#define GCAP 1536
__global__ __launch_bounds__(256) void gather_kernel(u16* __restrict__ A,
                                                     const int* __restrict__ row_ptr,
                                                     const int* __restrict__ csr_src, int n) {
  __shared__ int sidx[GCAP];                    // 6 KB
  int b = blockIdx.x;
  int slice = b & 7;
  int grp = b >> 3;
  int tid = threadIdx.x;
  int r0 = grp * 32;
  int rend = (r0 + 32 < n) ? (r0 + 32) : n;
  int wbeg = row_ptr[r0], wend = row_ptr[rend];
  int cnt = wend - wbeg;
  bool lds_ok = (cnt <= GCAP);
  if (lds_ok)
    for (int t = tid; t < cnt; t += 256) sidx[t] = csr_src[wbeg + t];
  __syncthreads();

  int wid = tid >> 6, lane = tid & 63;
  int dsub = lane >> 3, fl = lane & 7;
  int dst = r0 + wid * 8 + dsub;
  if (dst >= n) return;
  int cc = slice * 64 + fl * 8;                 // col within [0,512)
  const u16* Sx = A + DFEAT + cc;               // x-part base (+col), row stride KDIM
  int db = row_ptr[dst], de = row_ptr[dst + 1];
  float2 a[4] = {};
  if (lds_ok) {
    int e = db - wbeg, ee = de - wbeg;
    for (; e + 7 < ee; e += 8) {                // 8 loads in flight, idx via LDS
      int s0 = sidx[e + 0], s1 = sidx[e + 1], s2 = sidx[e + 2], s3 = sidx[e + 3];
      int s4 = sidx[e + 4], s5 = sidx[e + 5], s6 = sidx[e + 6], s7 = sidx[e + 7];
      uint4 v0 = *(const uint4*)&Sx[(size_t)s0 * KDIM];
      uint4 v1 = *(const uint4*)&Sx[(size_t)s1 * KDIM];
      uint4 v2 = *(const uint4*)&Sx[(size_t)s2 * KDIM];
      uint4 v3 = *(const uint4*)&Sx[(size_t)s3 * KDIM];
      uint4 v4 = *(const uint4*)&Sx[(size_t)s4 * KDIM];
      uint4 v5 = *(const uint4*)&Sx[(size_t)s5 * KDIM];
      uint4 v6 = *(const uint4*)&Sx[(size_t)s6 * KDIM];
      uint4 v7 = *(const uint4*)&Sx[(size_t)s7 * KDIM];
      add8(v0, a); add8(v1, a); add8(v2, a); add8(v3, a);
      add8(v4, a); add8(v5, a); add8(v6, a); add8(v7, a);
    }
    for (; e < ee; ++e) {
      uint4 v = *(const uint4*)&Sx[(size_t)sidx[e] * KDIM];
      add8(v, a);
    }
  } else {                                      // fallback (capacity exceeded)
    for (int e = db; e < de; ++e) {
      uint4 v = *(const uint4*)&Sx[(size_t)csr_src[e] * KDIM];
      add8(v, a);
    }
  }
  uint4 o;
  o.x = pack2(a[0].x, a[0].y); o.y = pack2(a[1].x, a[1].y);
  o.z = pack2(a[2].x, a[2].y); o.w = pack2(a[3].x, a[3].y);
  *(uint4*)&A[(size_t)dst * KDIM + cc] = o;
}

// ---------------- GEMM: Hb(bf16) = A(bf16) @ Wt^T(bf16) + bias, + BN stats ----------------
// 128x128 tile, BK=64, XOR-swizzled LDS staging; XCD-swizzled block mapping.
// Wave tile 64x64 = 2x2 of mfma_f32_32x32x16_bf16. LDS-staged coalesced epilogue.
#define BM 128
#define BN 128
#define BK 64
#define CSTR 132
__global__ __launch_bounds__(256, 4) void gemm_kernel(const u16* __restrict__ A,
                                                      const u16* __restrict__ Bt,
                                                      const float* __restrict__ bias,
                                                      u16* __restrict__ Hb,
                                                      float* __restrict__ sums, int M) {
  // lin -> (bx, by): xcd = lin&7; bx = (lin>>5)*8 + xcd; by = (lin>>3)&3
  const int lin = blockIdx.x;
  const int bx = ((lin >> 5) << 3) + (lin & 7);
  const int by = (lin >> 3) & 3;
  const int m0 = bx * BM;
  if (m0 >= M) return;
  const int n0 = by * BN;

  __shared__ u16 smem[BM * CSTR];   // 33 KB: K-loop As|Bs, epilogue C-tile
  __shared__ float sred[2 * BN];    // 1 KB
  u16* As = smem;
  u16* Bs = smem + BM * BK;
  const int tid = threadIdx.x;
  const int wid = tid >> 6, lane = tid & 63;
  const int wm = wid >> 1, wn = wid & 1;
  const int l31 = lane & 31, half = lane >> 5;

  if (tid < 2 * BN) sred[tid] = 0.f;

  // staging: wave wid, inst t: 8 rows (wid*32 + t*8 + dr), granule slot lane&7,
  // fetching global granule (lane&7)^dr (XOR swizzle, row&7 == dr)
  const int dr = lane >> 3;
  const int gcol = ((lane & 7) ^ dr) * 8;
  int arow[4], brow[4];
#pragma unroll
  for (int t = 0; t < 4; t++) {
    int r = wid * 32 + t * 8 + dr;
    int ar = m0 + r; if (ar >= M) ar = M - 1;   // clamp; stores/stats masked
    arow[t] = ar;
    brow[t] = n0 + r;                           // 512 rows: always valid
  }

  f32x16 acc[2][2] = {};

  for (int k0 = 0; k0 < KDIM; k0 += BK) {
    __syncthreads();   // previous iter's ds_reads done before DMA overwrite
#pragma unroll
    for (int t = 0; t < 4; t++)
      gload_lds16(&A[(size_t)arow[t] * KDIM + k0 + gcol], &As[(wid * 32 + t * 8) * BK]);
#pragma unroll
    for (int t = 0; t < 4; t++)
      gload_lds16(&Bt[(size_t)brow[t] * KDIM + k0 + gcol], &Bs[(wid * 32 + t * 8) * BK]);
    __syncthreads();   // DMA drain: tile visible
#pragma unroll
    for (int ks = 0; ks < 4; ks++) {            // 4 k-steps of K=16
      int slot = ((ks * 2 + half) ^ (l31 & 7)) * 8;
      bf16x8 a0 = *(const bf16x8*)&As[(wm * 64 + l31) * BK + slot];
      bf16x8 a1 = *(const bf16x8*)&As[(wm * 64 + 32 + l31) * BK + slot];
      bf16x8 b0 = *(const bf16x8*)&Bs[(wn * 64 + l31) * BK + slot];
      bf16x8 b1 = *(const bf16x8*)&Bs[(wn * 64 + 32 + l31) * BK + slot];
      acc[0][0] = __builtin_amdgcn_mfma_f32_32x32x16_bf16(a0, b0, acc[0][0], 0, 0, 0);
      acc[0][1] = __builtin_amdgcn_mfma_f32_32x32x16_bf16(a0, b1, acc[0][1], 0, 0, 0);
      acc[1][0] = __builtin_amdgcn_mfma_f32_32x32x16_bf16(a1, b0, acc[1][0], 0, 0, 0);
      acc[1][1] = __builtin_amdgcn_mfma_f32_32x32x16_bf16(a1, b1, acc[1][1], 0, 0, 0);
    }
  }

  __syncthreads();     // last iter's ds_reads done before C-tile overwrite

  // epilogue pass 1: acc -> LDS C-tile (bf16) + BN partial stats.
  // 32x32 D layout: col = lane&31, row = (reg&3) + 8*(reg>>2) + 4*(lane>>5).
#pragma unroll
  for (int nt = 0; nt < 2; nt++) {
    int colt = wn * 64 + nt * 32 + l31;
    float bv = bias[n0 + colt];
    float s = 0.f, s2 = 0.f;
#pragma unroll
    for (int mt = 0; mt < 2; mt++) {
      int rbase = wm * 64 + mt * 32 + half * 4;
#pragma unroll
      for (int reg = 0; reg < 16; reg++) {
        int rowt = rbase + (reg & 3) + 8 * (reg >> 2);
        float v = acc[mt][nt][reg] + bv;
        smem[rowt * CSTR + colt] = f2bf(v);
        if (m0 + rowt < M) { s += v; s2 += v * v; }
      }
    }
    s  += __shfl_xor(s, 32);
    s2 += __shfl_xor(s2, 32);
    if (half == 0) {
      atomicAdd(&sred[colt], s);
      atomicAdd(&sred[BN + colt], s2);
    }
  }
  __syncthreads();

  // epilogue pass 2: coalesced store (16 lanes x 16B = one 256B row chunk)
  const int rsub = tid >> 4;            // 0..15
  const int c8 = (tid & 15) * 8;
#pragma unroll
  for (int it = 0; it < 8; it++) {
    int rowt = it * 16 + rsub;
    int grow = m0 + rowt;
    if (grow < M) {
      uint4 v = *(const uint4*)&smem[rowt * CSTR + c8];
      *(uint4*)&Hb[(size_t)grow * DFEAT + n0 + c8] = v;
    }
  }
  if (tid < BN) {
    atomicAdd(&sums[n0 + tid], sred[tid]);
    atomicAdd(&sums[DFEAT + n0 + tid], sred[BN + tid]);
  }
}

// ---------------- norm: x = relu(H*sc+sh), finalize fused (N-scale) ----------------
__global__ void norm_kernel(const u16* __restrict__ Hb, const float* __restrict__ sums,
                            const float* __restrict__ gamma, const float* __restrict__ beta,
                            u16* __restrict__ A, int M, float invN) {
  int idx = blockIdx.x * 256 + threadIdx.x;      // 8 cols per thread
  int row = idx >> 6;
  int c8 = (idx & 63) * 8;
  if (row >= M) return;
  float sc[8], sh[8];
#pragma unroll
  for (int j = 0; j < 8; j++) {
    int c = c8 + j;
    float mu = sums[c] * invN;
    float var = sums[DFEAT + c] * invN - mu * mu;
    float s = gamma[c] * rsqrtf(var + BN_EPS);
    sc[j] = s;
    sh[j] = beta[c] - mu * s;
  }
  uint4 h = *(const uint4*)&Hb[(size_t)row * DFEAT + c8];
  float x0 = fmaxf(bf_lo(h.x) * sc[0] + sh[0], 0.f);
  float x1 = fmaxf(bf_hi(h.x) * sc[1] + sh[1], 0.f);
  float x2 = fmaxf(bf_lo(h.y) * sc[2] + sh[2], 0.f);
  float x3 = fmaxf(bf_hi(h.y) * sc[3] + sh[3], 0.f);
  float x4 = fmaxf(bf_lo(h.z) * sc[4] + sh[4], 0.f);
  float x5 = fmaxf(bf_hi(h.z) * sc[5] + sh[5], 0.f);
  float x6 = fmaxf(bf_lo(h.w) * sc[6] + sh[6], 0.f);
  float x7 = fmaxf(bf_hi(h.w) * sc[7] + sh[7], 0.f);
  uint4 o; o.x = pack2(x0, x1); o.y = pack2(x2, x3);
  o.z = pack2(x4, x5); o.w = pack2(x6, x7);
  *(uint4*)&A[(size_t)row * KDIM + DFEAT + c8] = o;
}

// ---------------- pooling (fused last-layer finalize+affine+ReLU) ----------------
__device__ __forceinline__ int lower_bound_dev(const int* a, int n, int v) {
  int lo = 0, hi = n;
  while (lo < hi) { int mid = (lo + hi) >> 1; if (a[mid] < v) lo = mid + 1; else hi = mid; }
  return lo;
}

__global__ __launch_bounds__(1024) void pool_kernel(const u16* __restrict__ Hb,
                                                    const float* __restrict__ sums,
                                                    const float* __restrict__ gamma,
                                                    const float* __restrict__ beta,
                                                    const int* __restrict__ batch,
                                                    float* __restrict__ pooled, int n, float invN) {
  __shared__ float red[DFEAT];
  int g = blockIdx.x;
  int tid = threadIdx.x;
  if (tid < DFEAT) red[tid] = 0.f;
  int lo = lower_bound_dev(batch, n, g);
  int hi = lower_bound_dev(batch, n, g + 1);
  int rowOff = tid >> 6, lane = tid & 63;
  int c0 = lane * 8;
  float sc[8], sh[8];
#pragma unroll
  for (int j = 0; j < 8; j++) {
    int c = c0 + j;
    float mu = sums[c] * invN;
    float var = sums[DFEAT + c] * invN - mu * mu;
    float s = gamma[c] * rsqrtf(var + BN_EPS);
    sc[j] = s;
    sh[j] = beta[c] - mu * s;
  }
  float a[8] = {};
  for (int r = lo + rowOff; r < hi; r += 16) {
    uint4 v = *(const uint4*)&Hb[(size_t)r * DFEAT + c0];
    float e0 = bf_lo(v.x), e1 = bf_hi(v.x), e2 = bf_lo(v.y), e3 = bf_hi(v.y);
    float e4 = bf_lo(v.z), e5 = bf_hi(v.z), e6 = bf_lo(v.w), e7 = bf_hi(v.w);
    a[0] += fmaxf(e0 * sc[0] + sh[0], 0.f); a[1] += fmaxf(e1 * sc[1] + sh[1], 0.f);
    a[2] += fmaxf(e2 * sc[2] + sh[2], 0.f); a[3] += fmaxf(e3 * sc[3] + sh[3], 0.f);
    a[4] += fmaxf(e4 * sc[4] + sh[4], 0.f); a[5] += fmaxf(e5 * sc[5] + sh[5], 0.f);
    a[6] += fmaxf(e6 * sc[6] + sh[6], 0.f); a[7] += fmaxf(e7 * sc[7] + sh[7], 0.f);
  }
  __syncthreads();
#pragma unroll
  for (int j = 0; j < 8; j++) atomicAdd(&red[c0 + j], a[j]);
  __syncthreads();
  if (tid < DFEAT) pooled[g * DFEAT + tid] = red[tid] / fmaxf((float)(hi - lo), 1.0f);
}

// wave per graph
__global__ __launch_bounds__(64) void final_kernel(const float* __restrict__ pooled,
                                                   const float* __restrict__ lin_w,
                                                   const float* __restrict__ lin_b,
                                                   float* __restrict__ out) {
  int g = blockIdx.x;
  int lane = threadIdx.x;
  float acc[NCLS] = {};
  float4 p0 = *(const float4*)&pooled[g * DFEAT + lane * 8];
  float4 p1 = *(const float4*)&pooled[g * DFEAT + lane * 8 + 4];
  float pv[8] = {p0.x, p0.y, p0.z, p0.w, p1.x, p1.y, p1.z, p1.w};
#pragma unroll
  for (int j = 0; j < 8; j++) {
    int k = lane * 8 + j;
#pragma unroll
    for (int c = 0; c < NCLS; c++) acc[c] += pv[j] * lin_w[k * NCLS + c];
  }
#pragma unroll
  for (int off = 32; off > 0; off >>= 1)
#pragma unroll
    for (int c = 0; c < NCLS; c++) acc[c] += __shfl_down(acc[c], off);
  if (lane == 0)
#pragma unroll
    for (int c = 0; c < NCLS; c++) out[g * NCLS + c] = acc[c] + lin_b[c];
}

// ---------------- orchestration ----------------
extern "C" void kernel_launch(void* const* d_in, const int* in_sizes, int n_in,
                              void* d_out, int out_size, void* d_ws, size_t ws_size,
                              hipStream_t stream) {
  const float* x      = (const float*)d_in[0];
  const int*   ei     = (const int*)d_in[1];
  const int*   batch  = (const int*)d_in[2];
  const float* W_rel  = (const float*)d_in[3];
  const float* b_rel  = (const float*)d_in[4];
  const float* W_root = (const float*)d_in[5];
  const float* gamma  = (const float*)d_in[6];
  const float* beta   = (const float*)d_in[7];
  const float* lin_w  = (const float*)d_in[8];
  const float* lin_b  = (const float*)d_in[9];
  float* out = (float*)d_out;

  const int N = in_sizes[0] / DFEAT;    // 20000
  const int E = in_sizes[1] / 2;        // 320000

  char* p = (char*)d_ws;
  u16*   A       = (u16*)p;    p += (size_t)N * KDIM * 2;
  u16*   Hb      = (u16*)p;    p += (size_t)N * DFEAT * 2;
  u16*   Wt      = (u16*)p;    p += (size_t)NLAYER * DFEAT * KDIM * 2;
  int*   row_ptr = (int*)p;    p += ((size_t)(N + 1) * 4 + 15) / 16 * 16;
  int*   cursor  = (int*)p;    p += (size_t)N * 4;   // doubles as counts
  int*   csr_src = (int*)p;    p += (size_t)E * 4;
  float* sums    = (float*)p;  p += (size_t)NLAYER * 2 * DFEAT * 4;
  float* pooled  = (float*)p;  p += (size_t)NGRAPH * DFEAT * 4;

  const float invN = 1.0f / (float)N;

  hipMemsetAsync(cursor, 0, (size_t)N * 4, stream);
  hipMemsetAsync(sums, 0, (size_t)NLAYER * 2 * DFEAT * 4, stream);

  // ---- merged prologue + CSR build ----
  const int histB = (E + 255) / 256;                  // 1250
  const int wB = (NLAYER * DFEAT * KDIM) / 256;       // 12288
  const int xB = (N * 128 + 255) / 256;               // 10000
  prep_kernel<<<histB + wB + xB, 256, 0, stream>>>(ei, cursor, E, W_rel, W_root, Wt,
                                                   x, A, N, histB, wB);
  scan_kernel<<<1, 1024, 0, stream>>>(cursor, row_ptr, cursor, N);
  scatter_kernel<<<(E + 255) / 256, 256, 0, stream>>>(ei, cursor, csr_src, E);

  const int ngrp8 = ((N + 31) / 32) * 8;              // 5000
  const int gtiles = (((N + BM - 1) / BM + 7) / 8) * 8 * 4;  // 640

  for (int l = 0; l < NLAYER; ++l) {
    float* sums_l = sums + (size_t)l * 2 * DFEAT;
    gather_kernel<<<ngrp8, 256, 0, stream>>>(A, row_ptr, csr_src, N);
    gemm_kernel<<<gtiles, 256, 0, stream>>>(A, Wt + (size_t)l * DFEAT * KDIM,
                                            b_rel + (size_t)l * DFEAT, Hb, sums_l, N);
    if (l < NLAYER - 1)
      norm_kernel<<<(N * 64 + 255) / 256, 256, 0, stream>>>(
          Hb, sums_l, gamma + (size_t)l * DFEAT, beta + (size_t)l * DFEAT, A, N, invN);
  }

  pool_kernel<<<NGRAPH, 1024, 0, stream>>>(Hb, sums + (size_t)(NLAYER - 1) * 2 * DFEAT,
                                           gamma + (size_t)(NLAYER - 1) * DFEAT,
                                           beta + (size_t)(NLAYER - 1) * DFEAT,
                                           batch, pooled, N, invN);
  final_kernel<<<NGRAPH, 64, 0, stream>>>(pooled, lin_w, lin_b, out);
}